// Round 5
// baseline (1278.407 us; speedup 1.0000x reference)
//
#include <hip/hip_runtime.h>
#include <hip/hip_bf16.h>
#include <hip/hip_fp16.h>

#define T_DIM 8192
#define H_DIM 3200
#define I_DIM 12800

typedef int v4i __attribute__((ext_vector_type(4)));
typedef int v16i __attribute__((ext_vector_type(16)));
typedef _Float16 h8 __attribute__((ext_vector_type(8)));

__device__ __forceinline__ void gload16(const void* g, void* l) {
    __builtin_amdgcn_global_load_lds(
        (const __attribute__((address_space(1))) unsigned int*)g,
        (__attribute__((address_space(3))) unsigned int*)l, 16, 0, 0);
}

// ---------------- int32 -> int8 repack (memory-bound) ----------------
__global__ __launch_bounds__(256) void repack_kernel(const int* __restrict__ src,
                                                     unsigned int* __restrict__ dst,
                                                     long n4) {
    long i = (long)blockIdx.x * blockDim.x + threadIdx.x;
    long stride = (long)gridDim.x * blockDim.x;
    for (; i < n4; i += stride) {
        int4 v = ((const int4*)src)[i];
        dst[i] = (unsigned int)((v.x & 255) | ((v.y & 255) << 8) |
                                ((v.z & 255) << 16) | ((v.w & 255) << 24));
    }
}

// ---------------- i8 GEMM, C[M][N] = A[M][K] * B[N][K]^T ----------------
// 128x128 tile, 256 threads = 4 waves (2M x 2N), per-wave 64x64 output via
// mfma_i32_32x32x32_i8 (acc 2x2 v16i = 64 VGPR). Ring-of-3 LDS slots per
// operand (3 x 8 KiB x 2 = 48 KiB) -> 3 blocks/CU co-resident (3 waves/SIMD):
// cross-block overlap hides phase-boundary latency (R0 evidence) WHILE the
// single-barrier counted-vmcnt phase keeps within-block overlap (R4 evidence).
// Phase (64-byte K-half h): { 8 ds_read_b128 ; stage A&B of half h+2 into the
// slot of half h-1 (4 gload16/thread) ; setprio1 ; 8 MFMA ; setprio0 ;
// vmcnt(4) ; s_barrier ; rotate }. Gate retires half h+1, leaves h+2's 4
// loads in flight -- never drained to 0.
// Ring-of-3 safety (skew <= 1 phase): stage(h+2) writes slot of h-1; every
// wave's reads of half h-1 were lgkm-complete before it crossed the
// end-of-(h-1) barrier (MFMAs consumed them pre-barrier).
//
// LDS placement: global_load_lds dest is LINEAR; bijection pi folded into the
// per-lane GLOBAL source so the fragment read is lane-for-lane identical to
// the round-1 pattern that measured 0 bank conflicts (per 2 KiB block of 32
// rows):  LDS (block, half, r15, col) holds global (row = block*32 +
// ((q&1)<<4) + r15, chunk = (half<<1)|(q>>1)), q = col ^ ((r15>>1)&3).
// strideA/strideB in BYTES. EPI=0: fp16 out. EPI=1: fp32 of fp16-rounded.
// No XCD swizzle (L3-resident regime: it tripled FETCH_SIZE in round 2).
template <int EPI>
__global__ __launch_bounds__(256, 3) void gemm_i8_128(
    const signed char* __restrict__ A, long strideA,
    const signed char* __restrict__ B, long strideB,
    int Ntrue, int K, int ldc,
    const float* __restrict__ rowscale, const float* __restrict__ colscale,
    const float* __restrict__ bias, void* __restrict__ Cout) {
    __shared__ signed char lds[49152];
    signed char* ldsA = lds;           // 3 slots x 8192 B (4 blocks of 2 KiB)
    signed char* ldsB = lds + 24576;   // 3 slots x 8192 B

    const int tid = threadIdx.x;
    const int lane = tid & 63, wid = tid >> 6;
    const int wr = wid >> 1, wc = wid & 1;
    const int bm = blockIdx.x, bn = blockIdx.y;
    const long Arow0 = (long)bm * 128;
    const long Bcol0 = (long)bn * 128;

    // Staging: slot = 512 chunks of 16 B; thread handles ch0 = tid and
    // ch1 = tid+256. LDS dest linear (ch*16); source row/chunk from pi.
    int g_row[2], g_cg[2];
#pragma unroll
    for (int u = 0; u < 2; ++u) {
        const int ch = tid + (u << 8);
        const int block = ch >> 7;
        const int p = ch & 127;
        const int half = (p >> 6) & 1;
        const int p6 = p & 63;
        const int r15 = p6 >> 2;
        const int col = p6 & 3;
        const int q = col ^ ((r15 >> 1) & 3);
        g_row[u] = block * 32 + ((q & 1) << 4) + r15;
        g_cg[u] = (half << 1) | (q >> 1);
    }
    const signed char* Ag0 = A + (Arow0 + g_row[0]) * strideA + g_cg[0] * 16;
    const signed char* Ag1 = A + (Arow0 + g_row[1]) * strideA + g_cg[1] * 16;
    const signed char* Bg0 = B + (Bcol0 + g_row[0]) * strideB + g_cg[0] * 16;
    const signed char* Bg1 = B + (Bcol0 + g_row[1]) * strideB + g_cg[1] * 16;
    const int d0 = tid * 16, d1 = (tid + 256) * 16;

    const int NH = K >> 6;  // number of 64-byte K-halves (phases)

    // Stage half h into ring slot (byte offset so_ within each operand region).
#define STAGE(h, so_)                            \
    {                                            \
        const int hc_ = (h) < NH ? (h) : NH - 1; \
        const long ko_ = (long)hc_ << 6;         \
        gload16(Ag0 + ko_, ldsA + (so_) + d0);   \
        gload16(Ag1 + ko_, ldsA + (so_) + d1);   \
        gload16(Bg0 + ko_, ldsB + (so_) + d0);   \
        gload16(Bg1 + ko_, ldsB + (so_) + d1);   \
    }

    // Fragment read offsets (round-1-proven conflict-free pattern per 1 KiB).
    const int rl = lane & 31, qh = lane >> 5;
    const int r15 = rl & 15, qb = rl >> 4;
    const int colr = ((qh << 1) | qb) ^ ((r15 >> 1) & 3);
    const int roff = r15 * 64 + colr * 16;    // within-block; ks=1: +1024
    const int aoff = (wr * 2) * 2048 + roff;  // + m*2048, m = 0..1
    const int boff = (wc * 2) * 2048 + roff;  // + n*2048, n = 0..1

    v16i acc[2][2] = {};

    // Prologue: stage halves 0,1 (8 loads); gate to 4 -> half 0 resident,
    // half 1 in flight (steady-state invariant entering phase 0).
    STAGE(0, 0);
    STAGE(1, 8192);
    asm volatile("s_waitcnt vmcnt(4)");
    __builtin_amdgcn_s_barrier();

    int so_cur = 0, so_nxt = 8192, so_stg = 16384;
    for (int h = 0; h < NH; ++h) {
        const signed char* sA = ldsA + so_cur;
        const signed char* sB = ldsB + so_cur;
        v4i a0[2], a1[2], b0[2], b1[2];
#pragma unroll
        for (int m = 0; m < 2; ++m) {
            a0[m] = *(const v4i*)(sA + aoff + m * 2048);
            a1[m] = *(const v4i*)(sA + aoff + m * 2048 + 1024);
        }
#pragma unroll
        for (int n = 0; n < 2; ++n) {
            b0[n] = *(const v4i*)(sB + boff + n * 2048);
            b1[n] = *(const v4i*)(sB + boff + n * 2048 + 1024);
        }
        // stage half h+2 into the slot of half h-1 (reads done before the
        // end-of-(h-1) barrier that every wave has crossed).
        STAGE(h + 2, so_stg);
        __builtin_amdgcn_s_setprio(1);
#pragma unroll
        for (int m = 0; m < 2; ++m)
#pragma unroll
            for (int n = 0; n < 2; ++n)
                acc[m][n] = __builtin_amdgcn_mfma_i32_32x32x32_i8(
                    a0[m], b0[n], acc[m][n], 0, 0, 0);
#pragma unroll
        for (int m = 0; m < 2; ++m)
#pragma unroll
            for (int n = 0; n < 2; ++n)
                acc[m][n] = __builtin_amdgcn_mfma_i32_32x32x32_i8(
                    a1[m], b1[n], acc[m][n], 0, 0, 0);
        __builtin_amdgcn_s_setprio(0);
        // counted gate: retire half h+1's 4 loads; leave half h+2's 4 in
        // flight. Never 0 in the main loop. Then the single per-phase barrier.
        asm volatile("s_waitcnt vmcnt(4)");
        __builtin_amdgcn_s_barrier();
        const int t = so_cur;
        so_cur = so_nxt;
        so_nxt = so_stg;
        so_stg = t;
    }

    // Epilogue: 32x32 C/D layout col = lane&31, row = (reg&3)+8*(reg>>2)+4*qh.
    const int row0 = bm * 128 + wr * 64;
    const int col0 = bn * 128 + wc * 64;
    const int rbase = 4 * qh;
#pragma unroll
    for (int m = 0; m < 2; ++m) {
#pragma unroll
        for (int n = 0; n < 2; ++n) {
            const int col = col0 + n * 32 + rl;
            if (col < Ntrue) {
                const float cs = colscale[col];
                const float bs = bias[col];
#pragma unroll
                for (int g = 0; g < 4; ++g) {
#pragma unroll
                    for (int rr = 0; rr < 4; ++rr) {
                        const int row = row0 + m * 32 + rbase + 8 * g + rr;
                        float v = (float)acc[m][n][g * 4 + rr];
                        v = __fmul_rn(v, rowscale[row]);
                        v = __fmul_rn(v, cs);
                        v = __fadd_rn(v, bs);
                        _Float16 hh = (_Float16)v;  // reference rounds to fp16
                        const size_t idx = (size_t)row * ldc + col;
                        if (EPI == 0) ((_Float16*)Cout)[idx] = hh;
                        else ((float*)Cout)[idx] = (float)hh;
                    }
                }
            }
        }
    }
#undef STAGE
}

// -------- exact GELU + per-token dynamic int8 requant (in-place act_q) -------
__global__ __launch_bounds__(256) void gelu_quant(_Float16* __restrict__ fc1,
                                                  float* __restrict__ nscale) {
    __shared__ float gbuf[I_DIM];
    __shared__ float wmax[4];
    const int tid = threadIdx.x, lane = tid & 63, wid = tid >> 6;
    const long t = blockIdx.x;
    const h8* row = (const h8*)(fc1 + t * I_DIM);
    float lmax = 0.f;
    for (int c = tid; c < I_DIM / 8; c += 256) {
        h8 v = row[c];
#pragma unroll
        for (int j = 0; j < 8; ++j) {
            float x = (float)v[j];
            float e = erff(__fdiv_rn(x, 1.41421356237309504880f));
            float g = __fmul_rn(__fmul_rn(0.5f, x), __fadd_rn(1.0f, e));
            gbuf[c * 8 + j] = g;
            lmax = fmaxf(lmax, fabsf(g));
        }
    }
#pragma unroll
    for (int off = 32; off; off >>= 1) lmax = fmaxf(lmax, __shfl_xor(lmax, off, 64));
    if (lane == 0) wmax[wid] = lmax;
    __syncthreads();
    const float gmax = fmaxf(fmaxf(wmax[0], wmax[1]), fmaxf(wmax[2], wmax[3]));
    const float ns = gmax / 127.0f;
    if (tid == 0) nscale[t] = ns;
    unsigned long long* out = (unsigned long long*)(fc1 + t * I_DIM);  // in-place
    for (int c = tid; c < I_DIM / 8; c += 256) {
        unsigned long long pk = 0;
#pragma unroll
        for (int j = 0; j < 8; ++j) {
            float qv = rintf(__fdiv_rn(gbuf[c * 8 + j], ns));
            qv = fminf(fmaxf(qv, -127.f), 127.f);
            pk |= ((unsigned long long)(unsigned char)(signed char)(int)qv) << (8 * j);
        }
        out[c] = pk;
    }
}

extern "C" void kernel_launch(void* const* d_in, const int* in_sizes, int n_in,
                              void* d_out, int out_size, void* d_ws, size_t ws_size,
                              hipStream_t stream) {
    const int* hs = (const int*)d_in[0];        // [B,S,H] int8-in-int32
    const float* scale = (const float*)d_in[1]; // [T]
    const int* w1 = (const int*)d_in[2];        // [I,H]
    const float* w1s = (const float*)d_in[3];   // [I]
    const float* b1 = (const float*)d_in[4];    // [I]
    const int* w2 = (const int*)d_in[5];        // [H,I]
    const float* w2s = (const float*)d_in[6];   // [H]
    const float* b2 = (const float*)d_in[7];    // [H]

    char* ws = (char*)d_ws;
    signed char* xq = (signed char*)ws;                     // 26,214,400 B
    signed char* w1q = xq + (size_t)T_DIM * H_DIM;          // 40,960,000 B
    signed char* w2q = w1q + (size_t)I_DIM * H_DIM;         // 40,960,000 B
    _Float16* fc1h = (_Float16*)(w2q + (size_t)H_DIM * I_DIM);  // chunkT*I fp16
    const size_t fixed = (size_t)T_DIM * H_DIM + 2 * (size_t)I_DIM * H_DIM;

    // choose smallest chunk count whose workspace fits ws_size (deterministic)
    int nc = 1;
    while (nc < 16) {
        size_t need = fixed + ((size_t)T_DIM / nc) * I_DIM * 2 +
                      ((size_t)T_DIM / nc) * 4 + 256;
        if (need <= ws_size) break;
        nc <<= 1;
    }
    const int chunkT = T_DIM / nc;
    float* nscale = (float*)((char*)fc1h + (size_t)chunkT * I_DIM * 2);

    repack_kernel<<<2048, 256, 0, stream>>>(hs, (unsigned int*)xq, (long)T_DIM * H_DIM / 4);
    repack_kernel<<<2048, 256, 0, stream>>>(w1, (unsigned int*)w1q, (long)I_DIM * H_DIM / 4);
    repack_kernel<<<2048, 256, 0, stream>>>(w2, (unsigned int*)w2q, (long)H_DIM * I_DIM / 4);

    for (int c = 0; c < nc; ++c) {
        const int t0 = c * chunkT;
        gemm_i8_128<0><<<dim3(chunkT / 128, I_DIM / 128), 256, 0, stream>>>(
            xq + (size_t)t0 * H_DIM, (long)H_DIM, w1q, (long)H_DIM,
            I_DIM, H_DIM, I_DIM,
            scale + t0, w1s, b1, (void*)fc1h);
        gelu_quant<<<chunkT, 256, 0, stream>>>(fc1h, nscale);
        gemm_i8_128<1><<<dim3(chunkT / 128, H_DIM / 128), 256, 0, stream>>>(
            (const signed char*)fc1h, (long)I_DIM * 2, w2q, (long)I_DIM,
            H_DIM, I_DIM, H_DIM,
            nscale, w2s, b2,
            (void*)((float*)d_out + (size_t)t0 * H_DIM));
    }
}

// Round 6
// 1045.518 us; speedup vs baseline: 1.2228x; 1.2228x over previous
//
#include <hip/hip_runtime.h>
#include <hip/hip_bf16.h>
#include <hip/hip_fp16.h>

#define T_DIM 8192
#define H_DIM 3200
#define I_DIM 12800

typedef int v4i __attribute__((ext_vector_type(4)));
typedef int v16i __attribute__((ext_vector_type(16)));
typedef _Float16 h8 __attribute__((ext_vector_type(8)));

__device__ __forceinline__ void gload16(const void* g, void* l) {
    __builtin_amdgcn_global_load_lds(
        (const __attribute__((address_space(1))) unsigned int*)g,
        (__attribute__((address_space(3))) unsigned int*)l, 16, 0, 0);
}

// ---------------- int32 -> int8 repack (memory-bound) ----------------
__global__ __launch_bounds__(256) void repack_kernel(const int* __restrict__ src,
                                                     unsigned int* __restrict__ dst,
                                                     long n4) {
    long i = (long)blockIdx.x * blockDim.x + threadIdx.x;
    long stride = (long)gridDim.x * blockDim.x;
    for (; i < n4; i += stride) {
        int4 v = ((const int4*)src)[i];
        dst[i] = (unsigned int)((v.x & 255) | ((v.y & 255) << 8) |
                                ((v.z & 255) << 16) | ((v.w & 255) << 24));
    }
}

// ---------------- i8 GEMM, C[M][N] = A[M][K] * B[N][K]^T ----------------
// 256x256 tile, 512 threads = 8 waves (2M x 4N), per-wave 128x64 output via
// mfma_i32_32x32x32_i8. 2-DEEP REGISTER PIPELINE over R4's single-barrier
// counted-vmcnt phase: phase h MFMAs on fragments prefetched during phase h-1
// while issuing ds_reads for half h+1 -- no lgkm dependency in front of the
// MFMA cluster (R4's ~2000cyc/phase stall was the serial read->wait->MFMA
// chain per wave). Loop unrolled by 2 with NAMED register sets (c/n) so all
// frag indices are compile-time constant (no scratch).
// Phase h: { 12 ds_read_b128 -> next-regs (half h+1) ; STAGE A&B of half h+3 ;
//            setprio1 ; 16 MFMA on cur-regs (half h) ; setprio0 ; vmcnt(4) ;
//            s_barrier }
// Ring-of-4 LDS slots/operand (4 x 16 KiB x 2 = 128 KiB). Ledger: gate
// vmcnt(4) at end of phase h retires half h+2's 4 loads (leaves h+3's 4 in
// flight; never 0) => entering phase h, halves h AND h+1 are resident (h+1 is
// the prefetch target). STAGE(h+3) writes slot (h-1)&3: its last readers
// (prefetch in phase h-2) were lgkm-drained by the MFMA of phase h-1, before
// the end-of-(h-1) barrier all waves crossed. NH is even for both GEMMs.
//
// LDS placement: global_load_lds dest is LINEAR; bijection pi folded into the
// per-lane GLOBAL source so the fragment read is lane-for-lane identical to
// the round-1 pattern that measured 0 bank conflicts (per 2 KiB block of 32
// rows):  LDS (block, half, r15, col) holds global (row = block*32 +
// ((q&1)<<4) + r15, chunk = (half<<1)|(q>>1)), q = col ^ ((r15>>1)&3).
// strideA/strideB in BYTES. EPI=0: fp16 out. EPI=1: fp32 of fp16-rounded.
// No XCD swizzle (L3-resident regime). fc2's N=3200: 13 col-guarded tiles.
template <int EPI>
__global__ __launch_bounds__(512, 2) void gemm_i8_pf(
    const signed char* __restrict__ A, long strideA,
    const signed char* __restrict__ B, long strideB,
    int Ntrue, int K, int ldc,
    const float* __restrict__ rowscale, const float* __restrict__ colscale,
    const float* __restrict__ bias, void* __restrict__ Cout) {
    __shared__ signed char lds[131072];
    signed char* ldsA = lds;           // 4 slots x 16384 B (8 blocks of 2 KiB)
    signed char* ldsB = lds + 65536;   // 4 slots x 16384 B

    const int tid = threadIdx.x;
    const int lane = tid & 63, wid = tid >> 6;
    const int wr = wid >> 2, wc = wid & 3;
    const int bm = blockIdx.x, bn = blockIdx.y;
    const long Arow0 = (long)bm * 256;
    const long Bcol0 = (long)bn * 256;

    // Staging: slot = 1024 chunks of 16 B; thread handles ch0 = tid and
    // ch1 = tid+512. LDS dest linear (ch*16); source row/chunk from pi.
    int g_row[2], g_cg[2];
#pragma unroll
    for (int u = 0; u < 2; ++u) {
        const int ch = tid + (u << 9);
        const int block = ch >> 7;
        const int p = ch & 127;
        const int half = (p >> 6) & 1;
        const int p6 = p & 63;
        const int r15 = p6 >> 2;
        const int col = p6 & 3;
        const int q = col ^ ((r15 >> 1) & 3);
        g_row[u] = block * 32 + ((q & 1) << 4) + r15;
        g_cg[u] = (half << 1) | (q >> 1);
    }
    const signed char* Ag0 = A + (Arow0 + g_row[0]) * strideA + g_cg[0] * 16;
    const signed char* Ag1 = A + (Arow0 + g_row[1]) * strideA + g_cg[1] * 16;
    const signed char* Bg0 = B + (Bcol0 + g_row[0]) * strideB + g_cg[0] * 16;
    const signed char* Bg1 = B + (Bcol0 + g_row[1]) * strideB + g_cg[1] * 16;
    const int d0 = tid * 16, d1 = (tid + 512) * 16;

    const int NH = K >> 6;  // number of 64-byte K-halves (phases); even

#define STAGE_A(h)                                  \
    {                                               \
        const int hc_ = (h) < NH ? (h) : NH - 1;    \
        const long ko_ = (long)hc_ << 6;            \
        signed char* d_ = ldsA + (((h) & 3) << 14); \
        gload16(Ag0 + ko_, d_ + d0);                \
        gload16(Ag1 + ko_, d_ + d1);                \
    }
#define STAGE_B(h)                                  \
    {                                               \
        const int hc_ = (h) < NH ? (h) : NH - 1;    \
        const long ko_ = (long)hc_ << 6;            \
        signed char* d_ = ldsB + (((h) & 3) << 14); \
        gload16(Bg0 + ko_, d_ + d0);                \
        gload16(Bg1 + ko_, d_ + d1);                \
    }

    // Fragment read offsets (round-1-proven conflict-free pattern per 1 KiB).
    const int rl = lane & 31, qh = lane >> 5;
    const int r15 = rl & 15, qb = rl >> 4;
    const int colr = ((qh << 1) | qb) ^ ((r15 >> 1) & 3);
    const int roff = r15 * 64 + colr * 16;  // within-block; ks=1: +1024
    const int aoff = (wr * 4) * 2048 + roff;  // + m*2048, m = 0..3
    const int boff = (wc * 2) * 2048 + roff;  // + n*2048, n = 0..1

    v16i acc[4][2] = {};

    // Prologue: stage halves 0,1,2 (12 loads); gate to 4 -> halves 0,1
    // resident, half 2 in flight. Then read frags(0) into the 'c' set.
    STAGE_A(0); STAGE_B(0); STAGE_A(1); STAGE_B(1); STAGE_A(2); STAGE_B(2);
    asm volatile("s_waitcnt vmcnt(4)");
    __builtin_amdgcn_s_barrier();

    v4i a0c[4], a1c[4], b0c[2], b1c[2];
    v4i a0n[4], a1n[4], b0n[2], b1n[2];
#pragma unroll
    for (int m = 0; m < 4; ++m) {
        a0c[m] = *(const v4i*)(ldsA + aoff + m * 2048);
        a1c[m] = *(const v4i*)(ldsA + aoff + m * 2048 + 1024);
    }
#pragma unroll
    for (int n = 0; n < 2; ++n) {
        b0c[n] = *(const v4i*)(ldsB + boff + n * 2048);
        b1c[n] = *(const v4i*)(ldsB + boff + n * 2048 + 1024);
    }

    // Phase macro: compute on Cxx (half h), prefetch half h+1 into Nxx.
#define PHASE(h, A0C, A1C, B0C, B1C, A0N, A1N, B0N, B1N)                  \
    {                                                                     \
        const int hn_ = ((h) + 1 < NH) ? (h) + 1 : NH - 1;                \
        const signed char* sA_ = ldsA + ((hn_ & 3) << 14);                \
        const signed char* sB_ = ldsB + ((hn_ & 3) << 14);                \
        _Pragma("unroll") for (int m = 0; m < 4; ++m) {                   \
            A0N[m] = *(const v4i*)(sA_ + aoff + m * 2048);                \
            A1N[m] = *(const v4i*)(sA_ + aoff + m * 2048 + 1024);         \
        }                                                                 \
        _Pragma("unroll") for (int n = 0; n < 2; ++n) {                   \
            B0N[n] = *(const v4i*)(sB_ + boff + n * 2048);                \
            B1N[n] = *(const v4i*)(sB_ + boff + n * 2048 + 1024);         \
        }                                                                 \
        STAGE_A((h) + 3);                                                 \
        STAGE_B((h) + 3);                                                 \
        __builtin_amdgcn_s_setprio(1);                                    \
        _Pragma("unroll") for (int m = 0; m < 4; ++m)                     \
            _Pragma("unroll") for (int n = 0; n < 2; ++n)                 \
                acc[m][n] = __builtin_amdgcn_mfma_i32_32x32x32_i8(        \
                    A0C[m], B0C[n], acc[m][n], 0, 0, 0);                  \
        _Pragma("unroll") for (int m = 0; m < 4; ++m)                     \
            _Pragma("unroll") for (int n = 0; n < 2; ++n)                 \
                acc[m][n] = __builtin_amdgcn_mfma_i32_32x32x32_i8(        \
                    A1C[m], B1C[n], acc[m][n], 0, 0, 0);                  \
        __builtin_amdgcn_s_setprio(0);                                    \
        asm volatile("s_waitcnt vmcnt(4)");                               \
        __builtin_amdgcn_s_barrier();                                     \
    }

    for (int h = 0; h < NH; h += 2) {
        PHASE(h, a0c, a1c, b0c, b1c, a0n, a1n, b0n, b1n);
        PHASE(h + 1, a0n, a1n, b0n, b1n, a0c, a1c, b0c, b1c);
    }

    // Epilogue: 32x32 C/D layout col = lane&31, row = (reg&3)+8*(reg>>2)+4*qh.
    const int row0 = bm * 256 + wr * 128;
    const int col0 = bn * 256 + wc * 64;
    const int rbase = 4 * qh;
#pragma unroll
    for (int m = 0; m < 4; ++m) {
#pragma unroll
        for (int n = 0; n < 2; ++n) {
            const int col = col0 + n * 32 + rl;
            if (col < Ntrue) {
                const float cs = colscale[col];
                const float bs = bias[col];
#pragma unroll
                for (int g = 0; g < 4; ++g) {
#pragma unroll
                    for (int rr = 0; rr < 4; ++rr) {
                        const int row = row0 + m * 32 + rbase + 8 * g + rr;
                        float v = (float)acc[m][n][g * 4 + rr];
                        v = __fmul_rn(v, rowscale[row]);
                        v = __fmul_rn(v, cs);
                        v = __fadd_rn(v, bs);
                        _Float16 hh = (_Float16)v;  // reference rounds to fp16
                        const size_t idx = (size_t)row * ldc + col;
                        if (EPI == 0) ((_Float16*)Cout)[idx] = hh;
                        else ((float*)Cout)[idx] = (float)hh;
                    }
                }
            }
        }
    }
#undef PHASE
#undef STAGE_A
#undef STAGE_B
}

// -------- exact GELU + per-token dynamic int8 requant (in-place act_q) -------
__global__ __launch_bounds__(256) void gelu_quant(_Float16* __restrict__ fc1,
                                                  float* __restrict__ nscale) {
    __shared__ float gbuf[I_DIM];
    __shared__ float wmax[4];
    const int tid = threadIdx.x, lane = tid & 63, wid = tid >> 6;
    const long t = blockIdx.x;
    const h8* row = (const h8*)(fc1 + t * I_DIM);
    float lmax = 0.f;
    for (int c = tid; c < I_DIM / 8; c += 256) {
        h8 v = row[c];
#pragma unroll
        for (int j = 0; j < 8; ++j) {
            float x = (float)v[j];
            float e = erff(__fdiv_rn(x, 1.41421356237309504880f));
            float g = __fmul_rn(__fmul_rn(0.5f, x), __fadd_rn(1.0f, e));
            gbuf[c * 8 + j] = g;
            lmax = fmaxf(lmax, fabsf(g));
        }
    }
#pragma unroll
    for (int off = 32; off; off >>= 1) lmax = fmaxf(lmax, __shfl_xor(lmax, off, 64));
    if (lane == 0) wmax[wid] = lmax;
    __syncthreads();
    const float gmax = fmaxf(fmaxf(wmax[0], wmax[1]), fmaxf(wmax[2], wmax[3]));
    const float ns = gmax / 127.0f;
    if (tid == 0) nscale[t] = ns;
    unsigned long long* out = (unsigned long long*)(fc1 + t * I_DIM);  // in-place
    for (int c = tid; c < I_DIM / 8; c += 256) {
        unsigned long long pk = 0;
#pragma unroll
        for (int j = 0; j < 8; ++j) {
            float qv = rintf(__fdiv_rn(gbuf[c * 8 + j], ns));
            qv = fminf(fmaxf(qv, -127.f), 127.f);
            pk |= ((unsigned long long)(unsigned char)(signed char)(int)qv) << (8 * j);
        }
        out[c] = pk;
    }
}

extern "C" void kernel_launch(void* const* d_in, const int* in_sizes, int n_in,
                              void* d_out, int out_size, void* d_ws, size_t ws_size,
                              hipStream_t stream) {
    const int* hs = (const int*)d_in[0];        // [B,S,H] int8-in-int32
    const float* scale = (const float*)d_in[1]; // [T]
    const int* w1 = (const int*)d_in[2];        // [I,H]
    const float* w1s = (const float*)d_in[3];   // [I]
    const float* b1 = (const float*)d_in[4];    // [I]
    const int* w2 = (const int*)d_in[5];        // [H,I]
    const float* w2s = (const float*)d_in[6];   // [H]
    const float* b2 = (const float*)d_in[7];    // [H]

    char* ws = (char*)d_ws;
    signed char* xq = (signed char*)ws;                     // 26,214,400 B
    signed char* w1q = xq + (size_t)T_DIM * H_DIM;          // 40,960,000 B
    signed char* w2q = w1q + (size_t)I_DIM * H_DIM;         // 40,960,000 B
    _Float16* fc1h = (_Float16*)(w2q + (size_t)H_DIM * I_DIM);  // chunkT*I fp16
    const size_t fixed = (size_t)T_DIM * H_DIM + 2 * (size_t)I_DIM * H_DIM;

    // choose smallest chunk count whose workspace fits ws_size (deterministic)
    int nc = 1;
    while (nc < 16) {
        size_t need = fixed + ((size_t)T_DIM / nc) * I_DIM * 2 +
                      ((size_t)T_DIM / nc) * 4 + 256;
        if (need <= ws_size) break;
        nc <<= 1;
    }
    const int chunkT = T_DIM / nc;
    float* nscale = (float*)((char*)fc1h + (size_t)chunkT * I_DIM * 2);

    repack_kernel<<<2048, 256, 0, stream>>>(hs, (unsigned int*)xq, (long)T_DIM * H_DIM / 4);
    repack_kernel<<<2048, 256, 0, stream>>>(w1, (unsigned int*)w1q, (long)I_DIM * H_DIM / 4);
    repack_kernel<<<2048, 256, 0, stream>>>(w2, (unsigned int*)w2q, (long)H_DIM * I_DIM / 4);

    const int n2tiles = (H_DIM + 255) / 256;  // 13; last tile col-guarded
    for (int c = 0; c < nc; ++c) {
        const int t0 = c * chunkT;
        gemm_i8_pf<0><<<dim3(chunkT / 256, I_DIM / 256), 512, 0, stream>>>(
            xq + (size_t)t0 * H_DIM, (long)H_DIM, w1q, (long)H_DIM,
            I_DIM, H_DIM, I_DIM,
            scale + t0, w1s, b1, (void*)fc1h);
        gelu_quant<<<chunkT, 256, 0, stream>>>(fc1h, nscale);
        gemm_i8_pf<1><<<dim3(chunkT / 256, n2tiles), 512, 0, stream>>>(
            (const signed char*)fc1h, (long)I_DIM * 2, w2q, (long)I_DIM,
            H_DIM, I_DIM, H_DIM,
            nscale, w2s, b2,
            (void*)((float*)d_out + (size_t)t0 * H_DIM));
    }
}

// Round 7
// 950.871 us; speedup vs baseline: 1.3445x; 1.0995x over previous
//
#include <hip/hip_runtime.h>
#include <hip/hip_bf16.h>
#include <hip/hip_fp16.h>

#define T_DIM 8192
#define H_DIM 3200
#define I_DIM 12800

typedef int v4i __attribute__((ext_vector_type(4)));
typedef _Float16 h8 __attribute__((ext_vector_type(8)));

__device__ __forceinline__ void gload16(const void* g, void* l) {
    __builtin_amdgcn_global_load_lds(
        (const __attribute__((address_space(1))) unsigned int*)g,
        (__attribute__((address_space(3))) unsigned int*)l, 16, 0, 0);
}

// ---------------- int32 -> int8 repack (memory-bound) ----------------
__global__ __launch_bounds__(256) void repack_kernel(const int* __restrict__ src,
                                                     unsigned int* __restrict__ dst,
                                                     long n4) {
    long i = (long)blockIdx.x * blockDim.x + threadIdx.x;
    long stride = (long)gridDim.x * blockDim.x;
    for (; i < n4; i += stride) {
        int4 v = ((const int4*)src)[i];
        dst[i] = (unsigned int)((v.x & 255) | ((v.y & 255) << 8) |
                                ((v.z & 255) << 16) | ((v.w & 255) << 24));
    }
}

// ---------------- i8 GEMM, C[M][N] = A[M][K] * B[N][K]^T ----------------
// ROUND-1 STRUCTURE (best measured GEMM: 416 us) + ROUND-4's single-barrier
// phase (its only isolated win: +9%). 256x256 tile, 512 threads = 8 waves
// (2M x 4N), per-wave 128x64, mfma_i32_16x16x64_i8. 8 phases per 2 K-tiles;
// each phase: { ds_read frag subtile ; issue 1 staging unit ; setprio1 ;
// 16 MFMA ; setprio0 ; [vmcnt(6) at ph3] ; s_barrier }.
// Mid-phase barrier + explicit lgkmcnt(0) REMOVED (R4 evidence): compiler
// inserts per-consumer lgkm waits; waves skew within a phase so one wave's
// ds_reads overlap another's MFMAs; one convergence per phase instead of two.
// Safety (skew <= 1 phase): STAGE at phase p targets a slot whose last
// readers issued reads at phase <= p-1; those reads were lgkm-complete before
// their wave crossed barrier p-1, and the stager stages only after crossing
// barrier p-1. Gate vmcnt(6) once per K-tile (3 units = 6 loads in flight,
// never drained to 0) -- ledger identical to round 1 (audited, passed).
// LDS: ring of 4 half-K-tile units per operand (4 x 16 KiB x 2 = 128 KiB).
// global_load_lds dest LINEAR; XOR swizzle (16B chunk cc ^= (row>>1)&3)
// pre-applied to the per-lane GLOBAL source and to ds_read addrs (0-conflict,
// measured). strideA/strideB in BYTES. EPI=0: fp16 out; EPI=1: fp32 of
// fp16-rounded. fc2's N=3200 runs on 13 col-guarded tiles.
template <int EPI>
__global__ __launch_bounds__(512, 2) void gemm_i8_8ph(
    const signed char* __restrict__ A, long strideA,
    const signed char* __restrict__ B, long strideB,
    int Ntrue, int K, int ldc,
    const float* __restrict__ rowscale, const float* __restrict__ colscale,
    const float* __restrict__ bias, void* __restrict__ Cout) {
    __shared__ signed char lds[131072];
    signed char* ldsA = lds;           // 4 units x 16384 B (256 rows x 64 B)
    signed char* ldsB = lds + 65536;   // 4 units x 16384 B

    const int tid = threadIdx.x;
    const int lane = tid & 63, wid = tid >> 6;
    const int wr = wid >> 2, wc = wid & 3;
    const int bm = blockIdx.x, bn = blockIdx.y;
    const long Arow0 = (long)bm * 256;
    const long Bcol0 = (long)bn * 256;

    // Staging: unit = 256 rows x 64 B = 1024 chunks of 16 B; thread handles
    // chunks c0 = tid and c1 = tid+512. LDS dest is linear (uniform base +
    // lane*16); the swizzle is folded into the per-lane GLOBAL source chunk.
    const int c0 = tid, c1 = tid + 512;
    const int r0 = c0 >> 2, r1 = c1 >> 2;
    const int s0 = (((c0 & 3) ^ ((r0 >> 1) & 3)) << 4);
    const int s1 = (((c1 & 3) ^ ((r1 >> 1) & 3)) << 4);
    const signed char* Ag0 = A + (Arow0 + r0) * strideA + s0;
    const signed char* Ag1 = A + (Arow0 + r1) * strideA + s1;
    const signed char* Bg0 = B + (Bcol0 + r0) * strideB + s0;
    const signed char* Bg1 = B + (Bcol0 + r1) * strideB + s1;
    const int d0 = c0 * 16, d1 = c1 * 16;

    const int NH = K >> 6;   // number of 64-byte K-halves
    const int nkt = K >> 7;  // loop bodies (1 K-tile = 2 halves = 4 phases)

#define STAGE_A(h)                                  \
    {                                               \
        const int hc_ = (h) < NH ? (h) : NH - 1;    \
        const long ko_ = (long)hc_ << 6;            \
        signed char* d_ = ldsA + (((h) & 3) << 14); \
        gload16(Ag0 + ko_, d_ + d0);                \
        gload16(Ag1 + ko_, d_ + d1);                \
    }
#define STAGE_B(h)                                  \
    {                                               \
        const int hc_ = (h) < NH ? (h) : NH - 1;    \
        const long ko_ = (long)hc_ << 6;            \
        signed char* d_ = ldsB + (((h) & 3) << 14); \
        gload16(Bg0 + ko_, d_ + d0);                \
        gload16(Bg1 + ko_, d_ + d1);                \
    }

    // Fragment read offsets: lane reads 16 B at (row, k-chunk q) -> LDS chunk
    // q ^ ((row>>1)&3); per-lane constant swz. Frag i lives at +i*1024.
    const int r = lane & 15, q = lane >> 4;
    const int swz = ((q ^ ((r >> 1) & 3)) << 4);
    const int aoff = (wr * 128 + r) * 64 + swz;  // + i*1024, i = 0..7
    const int boff = (wc * 64 + r) * 64 + swz;   // + n*1024, n = 0..3

    v4i acc[8][4] = {};
    v4i af[4], bf[4];

    // Phase: read frags -> issue 1 stage -> setprio(1) -> 16 MFMA ->
    // setprio(0) -> [gate] -> ONE barrier. (No mid-phase barrier/lgkm drain:
    // compiler inserts per-consumer lgkm waits; R4 evidence.)
#define PHASE(SLOTA, SLOTB, AIDX, LOADB, ACCOFF, STAGE_STMT, GATE_STMT)     \
    {                                                                       \
        _Pragma("unroll") for (int i = 0; i < 4; ++i)                       \
            af[i] = *(const v4i*)((SLOTA) + aoff + ((AIDX) + i) * 1024);    \
        if (LOADB) {                                                        \
            _Pragma("unroll") for (int n = 0; n < 4; ++n)                   \
                bf[n] = *(const v4i*)((SLOTB) + boff + n * 1024);           \
        }                                                                   \
        STAGE_STMT;                                                         \
        __builtin_amdgcn_s_setprio(1);                                      \
        _Pragma("unroll") for (int m = 0; m < 4; ++m)                       \
            _Pragma("unroll") for (int n = 0; n < 4; ++n)                   \
                acc[m + (ACCOFF)][n] = __builtin_amdgcn_mfma_i32_16x16x64_i8( \
                    af[m], bf[n], acc[m + (ACCOFF)][n], 0, 0, 0);           \
        __builtin_amdgcn_s_setprio(0);                                      \
        GATE_STMT;                                                          \
        __builtin_amdgcn_s_barrier();                                       \
    }

    // Prologue: stage stream prefix B0,A0,B1,A1,B2,A2,B3; gate leaves the
    // newest 3 units (6 loads) in flight -- halves 0,1 guaranteed resident.
    STAGE_B(0); STAGE_A(0); STAGE_B(1); STAGE_A(1);
    STAGE_B(2); STAGE_A(2); STAGE_B(3);
    asm volatile("s_waitcnt vmcnt(6)");
    __builtin_amdgcn_s_barrier();

    for (int kt = 0; kt < nkt; ++kt) {
        const int g = kt << 1;
        const signed char* sA0 = ldsA + ((g & 3) << 14);
        const signed char* sB0 = ldsB + ((g & 3) << 14);
        const signed char* sA1 = ldsA + (((g + 1) & 3) << 14);
        const signed char* sB1 = ldsB + (((g + 1) & 3) << 14);
        // ph0: half g,   A0-3 x B0-3 ; stage A(g+3) (slot of A(g-1), read ph2/3 of kt-1)
        PHASE(sA0, sB0, 0, true, 0, STAGE_A(g + 3), );
        // ph1: half g,   A4-7 x B0-3 ; stage B(g+4) (slot of B(g), read ph0)
        PHASE(sA0, sB0, 4, false, 4, STAGE_B(g + 4), );
        // ph2: half g+1, A0-3 x B0-3 ; stage A(g+4) (slot of A(g), read ph0-1)
        PHASE(sA1, sB1, 0, true, 0, STAGE_A(g + 4), );
        // ph3: half g+1, A4-7 x B0-3 ; stage B(g+5); counted gate vmcnt(6)
        PHASE(sA1, sB1, 4, false, 4, STAGE_B(g + 5),
              asm volatile("s_waitcnt vmcnt(6)"));
    }

    // Epilogue: C/D layout col = lane&15, row = (lane>>4)*4 + reg.
    const int row0 = bm * 256 + wr * 128;
    const int col0 = bn * 256 + wc * 64;
    const int r4 = (lane >> 4) << 2, cl = lane & 15;
#pragma unroll
    for (int m = 0; m < 8; ++m) {
        const int rowb = row0 + m * 16 + r4;
        float rs[4];
#pragma unroll
        for (int rr = 0; rr < 4; ++rr) rs[rr] = rowscale[rowb + rr];
#pragma unroll
        for (int n = 0; n < 4; ++n) {
            const int col = col0 + n * 16 + cl;
            if (col < Ntrue) {
                const float cs = colscale[col];
                const float bs = bias[col];
#pragma unroll
                for (int rr = 0; rr < 4; ++rr) {
                    float v = (float)acc[m][n][rr];
                    v = __fmul_rn(v, rs[rr]);
                    v = __fmul_rn(v, cs);
                    v = __fadd_rn(v, bs);
                    _Float16 hh = (_Float16)v;  // reference rounds to fp16
                    const size_t idx = (size_t)(rowb + rr) * ldc + col;
                    if (EPI == 0) ((_Float16*)Cout)[idx] = hh;
                    else ((float*)Cout)[idx] = (float)hh;
                }
            }
        }
    }
#undef PHASE
#undef STAGE_A
#undef STAGE_B
}

// -------- exact GELU + per-token dynamic int8 requant (in-place act_q) -------
__global__ __launch_bounds__(256) void gelu_quant(_Float16* __restrict__ fc1,
                                                  float* __restrict__ nscale) {
    __shared__ float gbuf[I_DIM];
    __shared__ float wmax[4];
    const int tid = threadIdx.x, lane = tid & 63, wid = tid >> 6;
    const long t = blockIdx.x;
    const h8* row = (const h8*)(fc1 + t * I_DIM);
    float lmax = 0.f;
    for (int c = tid; c < I_DIM / 8; c += 256) {
        h8 v = row[c];
#pragma unroll
        for (int j = 0; j < 8; ++j) {
            float x = (float)v[j];
            float e = erff(__fdiv_rn(x, 1.41421356237309504880f));
            float g = __fmul_rn(__fmul_rn(0.5f, x), __fadd_rn(1.0f, e));
            gbuf[c * 8 + j] = g;
            lmax = fmaxf(lmax, fabsf(g));
        }
    }
#pragma unroll
    for (int off = 32; off; off >>= 1) lmax = fmaxf(lmax, __shfl_xor(lmax, off, 64));
    if (lane == 0) wmax[wid] = lmax;
    __syncthreads();
    const float gmax = fmaxf(fmaxf(wmax[0], wmax[1]), fmaxf(wmax[2], wmax[3]));
    const float ns = gmax / 127.0f;
    if (tid == 0) nscale[t] = ns;
    unsigned long long* out = (unsigned long long*)(fc1 + t * I_DIM);  // in-place
    for (int c = tid; c < I_DIM / 8; c += 256) {
        unsigned long long pk = 0;
#pragma unroll
        for (int j = 0; j < 8; ++j) {
            float qv = rintf(__fdiv_rn(gbuf[c * 8 + j], ns));
            qv = fminf(fmaxf(qv, -127.f), 127.f);
            pk |= ((unsigned long long)(unsigned char)(signed char)(int)qv) << (8 * j);
        }
        out[c] = pk;
    }
}

extern "C" void kernel_launch(void* const* d_in, const int* in_sizes, int n_in,
                              void* d_out, int out_size, void* d_ws, size_t ws_size,
                              hipStream_t stream) {
    const int* hs = (const int*)d_in[0];        // [B,S,H] int8-in-int32
    const float* scale = (const float*)d_in[1]; // [T]
    const int* w1 = (const int*)d_in[2];        // [I,H]
    const float* w1s = (const float*)d_in[3];   // [I]
    const float* b1 = (const float*)d_in[4];    // [I]
    const int* w2 = (const int*)d_in[5];        // [H,I]
    const float* w2s = (const float*)d_in[6];   // [H]
    const float* b2 = (const float*)d_in[7];    // [H]

    char* ws = (char*)d_ws;
    signed char* xq = (signed char*)ws;                     // 26,214,400 B
    signed char* w1q = xq + (size_t)T_DIM * H_DIM;          // 40,960,000 B
    signed char* w2q = w1q + (size_t)I_DIM * H_DIM;         // 40,960,000 B
    _Float16* fc1h = (_Float16*)(w2q + (size_t)H_DIM * I_DIM);  // chunkT*I fp16
    const size_t fixed = (size_t)T_DIM * H_DIM + 2 * (size_t)I_DIM * H_DIM;

    // choose smallest chunk count whose workspace fits ws_size (deterministic)
    int nc = 1;
    while (nc < 16) {
        size_t need = fixed + ((size_t)T_DIM / nc) * I_DIM * 2 +
                      ((size_t)T_DIM / nc) * 4 + 256;
        if (need <= ws_size) break;
        nc <<= 1;
    }
    const int chunkT = T_DIM / nc;
    float* nscale = (float*)((char*)fc1h + (size_t)chunkT * I_DIM * 2);

    repack_kernel<<<2048, 256, 0, stream>>>(hs, (unsigned int*)xq, (long)T_DIM * H_DIM / 4);
    repack_kernel<<<2048, 256, 0, stream>>>(w1, (unsigned int*)w1q, (long)I_DIM * H_DIM / 4);
    repack_kernel<<<2048, 256, 0, stream>>>(w2, (unsigned int*)w2q, (long)H_DIM * I_DIM / 4);

    const int n2tiles = (H_DIM + 255) / 256;  // 13; last tile col-guarded
    for (int c = 0; c < nc; ++c) {
        const int t0 = c * chunkT;
        gemm_i8_8ph<0><<<dim3(chunkT / 256, I_DIM / 256), 512, 0, stream>>>(
            xq + (size_t)t0 * H_DIM, (long)H_DIM, w1q, (long)H_DIM,
            I_DIM, H_DIM, I_DIM,
            scale + t0, w1s, b1, (void*)fc1h);
        gelu_quant<<<chunkT, 256, 0, stream>>>(fc1h, nscale);
        gemm_i8_8ph<1><<<dim3(chunkT / 256, n2tiles), 512, 0, stream>>>(
            (const signed char*)fc1h, (long)I_DIM * 2, w2q, (long)I_DIM,
            H_DIM, I_DIM, H_DIM,
            nscale, w2s, b2,
            (void*)((float*)d_out + (size_t)t0 * H_DIM));
    }
}